// Round 1
// baseline (259.284 us; speedup 1.0000x reference)
//
#include <hip/hip_runtime.h>

// DiscreteKeyValueBottleneck on MI355X (gfx950)
// B=4 T=1024 H=12 C=4096 DK=DV=64, N=B*T=4096, DIM=768
//
// Round 7: pass-1 was mixed VALU/barrier-bound (MfmaUtil 28, VALUBusy 47,
// 64 __syncthreads forcing vmcnt(0) drains). Changes:
//  * 2-product scores: fp16(x)*fp16(64*E)_hi + bf16(x)*bf16(residual)
//    -> 8 MFMA/tile instead of 12 (split-bf16). E scaled x64 => no f16
//    denormal inputs. Error budget ~2e-5 << TAU.
//  * top-2 update 3 VALU/score: chunk index packed into score mantissa
//    low 6 bits (and_or+med3+max); index decoded in epilogue.
//  * 4 waves share ONE code-half (128 q/block), 64-code chunks (32 iters),
//    3-buffer LDS ring, raw s_barrier + counted s_waitcnt vmcnt(4)
//    (depth-2 prefetch survives barriers; no per-iter drain).
//  * m2(-e2/2, bf16, x64 scale) staged in LDS (keeps vmcnt count clean).
//  * cross-half merge + margin flag + values gather in a small 4th kernel.
//  * recheck (numpy-bit-exact) unchanged; TAU 5e-5 -> 8e-5 (x64: 5.12e-3).

#define HEADS 12
#define CODES 4096
#define DKI   64
#define DVI   64
#define DIMX  768
#define TAUS  5.12e-3f    // 64 * 8e-5 (scores carry the x64 E-scale)
#define WLCAP 32768

typedef short bf16x8 __attribute__((ext_vector_type(8)));
typedef _Float16 f16x8 __attribute__((ext_vector_type(8)));
typedef float f32x16 __attribute__((ext_vector_type(16)));

__device__ __forceinline__ unsigned short f2bf(float f) {   // RNE
    unsigned int u = __float_as_uint(f);
    return (unsigned short)((u + 0x7fff + ((u >> 16) & 1)) >> 16);
}
__device__ __forceinline__ float bf2f(unsigned short h) {
    return __uint_as_float(((unsigned int)h) << 16);
}
__device__ __forceinline__ unsigned short f2h(float f) {    // RNE f32->f16
    _Float16 h = (_Float16)f;
    unsigned short u;
    __builtin_memcpy(&u, &h, 2);
    return u;
}
__device__ __forceinline__ float h2f(unsigned short u) {
    _Float16 h;
    __builtin_memcpy(&h, &u, 2);
    return (float)h;
}

__device__ __forceinline__ void async_load16(const void* g, void* l) {
    __builtin_amdgcn_global_load_lds(
        (const __attribute__((address_space(1))) unsigned int*)g,
        (__attribute__((address_space(3))) unsigned int*)l, 16, 0, 0);
}

// ---------------- numpy bit-exact helpers (fp32, contraction OFF) -----------
__device__ __forceinline__ float np_sumsq64(const float* __restrict__ a) {
#pragma clang fp contract(off)
    float r[8];
#pragma unroll
    for (int j = 0; j < 8; ++j) r[j] = a[j] * a[j];
#pragma unroll
    for (int i = 8; i < 64; i += 8)
#pragma unroll
        for (int j = 0; j < 8; ++j) r[j] += a[i + j] * a[i + j];
    return ((r[0] + r[1]) + (r[2] + r[3])) + ((r[4] + r[5]) + (r[6] + r[7]));
}

__device__ __forceinline__ float np_dot64(const float* __restrict__ xx,
                                          const float* __restrict__ ee) {
#pragma clang fp contract(off)
    float S0 = 0.f, S1 = 0.f, S2 = 0.f, S3 = 0.f;
#pragma unroll
    for (int t = 0; t < 64; t += 16) {
        float p[16];
#pragma unroll
        for (int j = 0; j < 16; ++j) p[j] = xx[t + j] * ee[t + j];
        S0 = p[0] + (p[4] + (p[8]  + (p[12] + S0)));
        S1 = p[1] + (p[5] + (p[9]  + (p[13] + S1)));
        S2 = p[2] + (p[6] + (p[10] + (p[14] + S2)));
        S3 = p[3] + (p[7] + (p[11] + (p[15] + S3)));
    }
    return (S0 + S1) + (S2 + S3);
}

// ---- prep: np-exact e2; Eh(fp16,x64)/El(bf16 residual) chunk-piece layout --
// uint4 units: [((pair*64 + gg)*8 + piece)*32 + (c&31)], pair = h*2+half,
// gg = (c&2047)>>5. Per 32-code group: 8 pieces x 32 codes x 16B = 4KB.
__global__ __launch_bounds__(256) void prep_ke(const float* __restrict__ ke,
                                               uint4* __restrict__ EhT,
                                               uint4* __restrict__ ElT,
                                               float* __restrict__ e2np,
                                               unsigned short* __restrict__ m2bf,
                                               int* __restrict__ wl_count) {
    if (blockIdx.x == 0 && threadIdx.x == 0) *wl_count = 0;
    int idx = blockIdx.x * 256 + threadIdx.x;
    if (idx >= HEADS * CODES) return;
    float er[DKI];
    const float4* p4 = reinterpret_cast<const float4*>(ke + (size_t)idx * DKI);
#pragma unroll
    for (int i = 0; i < DKI / 4; ++i) {
        float4 v = p4[i];
        er[i * 4 + 0] = v.x; er[i * 4 + 1] = v.y;
        er[i * 4 + 2] = v.z; er[i * 4 + 3] = v.w;
    }
    float e2 = np_sumsq64(er);
    e2np[idx] = e2;

    int h = idx >> 12, c = idx & 4095;
    int half = c >> 11, cw = c & 2047, gg = cw >> 5, cc = c & 31;
    int pair = h * 2 + half;
    m2bf[pair * 2048 + cw] = f2bf(-32.f * e2);   // 64 * (-e2/2), bf16

    size_t base = ((size_t)(pair * 64 + gg) * 8) * 32 + cc;
#pragma unroll
    for (int p = 0; p < 8; ++p) {
        unsigned int hb[8], lb[8];
#pragma unroll
        for (int j = 0; j < 8; ++j) {
            float fs = er[p * 8 + j] * 64.f;      // exact (pow2 scale)
            unsigned short hh = f2h(fs);
            hb[j] = hh;
            float el = fs - h2f(hh);              // exact residual
            lb[j] = f2bf(el);
        }
        uint4 hv, lv;
        hv.x = hb[0] | (hb[1] << 16); hv.y = hb[2] | (hb[3] << 16);
        hv.z = hb[4] | (hb[5] << 16); hv.w = hb[6] | (hb[7] << 16);
        lv.x = lb[0] | (lb[1] << 16); lv.y = lb[2] | (lb[3] << 16);
        lv.z = lb[4] | (lb[5] << 16); lv.w = lb[6] | (lb[7] << 16);
        EhT[base + p * 32] = hv;
        ElT[base + p * 32] = lv;
    }
}

// ---- pass 1: fp16+bf16 2-product MFMA, counted-vmcnt 3-buffer ring ---------
// grid 768 = 24 pairs x 32 q-blocks; pair = b%24 (24%8==0 => XCD-pinned).
// Block: 4 waves, 128 queries, ONE code half (2048 codes, 32x 64-code chunks).
// Wave w stages matrix (w&1) of group (w>>1) each chunk; all consume all.
__global__ __launch_bounds__(256, 3) void dkvb_pass1(
        const float* __restrict__ x,
        const char* __restrict__ EhT,
        const char* __restrict__ ElT,
        const unsigned short* __restrict__ m2bf,
        float* __restrict__ wsv, float* __restrict__ wsv2,
        int* __restrict__ wsi) {
    __shared__ __align__(16) char ldsbuf[3][16384];   // 64 codes x (Eh|El) x 2 grp
    __shared__ __align__(16) unsigned short m2s[2048];

    const int tid  = threadIdx.x;
    const int pr   = blockIdx.x % 24;        // pair = h*2 + half
    const int qb   = blockIdx.x / 24;
    const int h    = pr >> 1;
    const int w    = tid >> 6;
    const int lane = tid & 63;
    const int col  = lane & 31;              // B col (code) / A row (query)
    const int kh   = lane >> 5;              // k-half within K=16 step
    const int q0   = qb * 128;

    // ---- A fragments: query m = q0 + w*32 + col; step t: k = t*16 + kh*8 + j
    const float* xrow = x + (size_t)(q0 + w * 32 + col) * DIMX + h * DKI;
    f16x8 ah[4]; bf16x8 ab[4];
#pragma unroll
    for (int t = 0; t < 4; ++t) {
        const float* p = xrow + t * 16 + kh * 8;
        float4 v0 = *reinterpret_cast<const float4*>(p);
        float4 v1 = *reinterpret_cast<const float4*>(p + 4);
        float f[8] = {v0.x, v0.y, v0.z, v0.w, v1.x, v1.y, v1.z, v1.w};
#pragma unroll
        for (int j = 0; j < 8; ++j) {
            ah[t][j] = (_Float16)f[j];
            ab[t][j] = (short)f2bf(f[j]);
        }
    }

    // ---- stage m2 (bf16, x64 scale) for this half into LDS ----------------
    ((uint4*)m2s)[tid] = ((const uint4*)(m2bf + pr * 2048))[tid];
    asm volatile("s_waitcnt lgkmcnt(0)" ::: "memory");

    // ---- staging role + prologue (chunks 0,1) -----------------------------
    const int g   = w >> 1;
    const int mat = w & 1;
    const char* gsrc = (mat ? ElT : EhT)
                     + ((size_t)(pr * 64 + g)) * 4096 + (size_t)lane * 16;
    const unsigned ldso = (unsigned)(g * 2 + mat) * 4096u;

    char* bA = &ldsbuf[0][0];
    char* bB = &ldsbuf[1][0];
    char* bC = &ldsbuf[2][0];

    auto STAGE = [&](const char* gp, char* lp) {
        async_load16(gp,        lp);
        async_load16(gp + 1024, lp + 1024);
        async_load16(gp + 2048, lp + 2048);
        async_load16(gp + 3072, lp + 3072);
    };
    STAGE(gsrc,        bA + ldso);
    STAGE(gsrc + 8192, bB + ldso);

    float bv[16], bv2[16];
#pragma unroll
    for (int r = 0; r < 16; ++r) { bv[r] = -1e30f; bv2[r] = -1e30f; }

    const int foff = (kh * 32 + col) * 16;   // + t*1024 (piece 2t+kh)

#pragma unroll 1
    for (int i = 0; i < 32; ++i) {
        // counted prefetch: chunks i, i+1 in flight (4 loads each per wave)
        if (i < 31) { asm volatile("s_waitcnt vmcnt(4)" ::: "memory"); }
        else        { asm volatile("s_waitcnt vmcnt(0)" ::: "memory"); }
        __builtin_amdgcn_sched_barrier(0);
        __builtin_amdgcn_s_barrier();        // chunk i valid for all waves
        __builtin_amdgcn_sched_barrier(0);
        if (i + 2 < 32) STAGE(gsrc + (size_t)(i + 2) * 8192, bC + ldso);

#pragma unroll
        for (int g2 = 0; g2 < 2; ++g2) {
            const char* Bb = bA + g2 * 8192 + foff;
            f16x8 bh[4]; bf16x8 bl[4];
#pragma unroll
            for (int t = 0; t < 4; ++t) {
                bh[t] = *reinterpret_cast<const f16x8*>(Bb + t * 1024);
                bl[t] = *reinterpret_cast<const bf16x8*>(Bb + 4096 + t * 1024);
            }
            float m2v = bf2f(m2s[(2 * i + g2) * 32 + col]);
            f32x16 acc;
#pragma unroll
            for (int r = 0; r < 16; ++r) acc[r] = m2v;

            acc = __builtin_amdgcn_mfma_f32_32x32x16_f16 (ah[0], bh[0], acc, 0, 0, 0);
            acc = __builtin_amdgcn_mfma_f32_32x32x16_f16 (ah[1], bh[1], acc, 0, 0, 0);
            acc = __builtin_amdgcn_mfma_f32_32x32x16_f16 (ah[2], bh[2], acc, 0, 0, 0);
            acc = __builtin_amdgcn_mfma_f32_32x32x16_f16 (ah[3], bh[3], acc, 0, 0, 0);
            acc = __builtin_amdgcn_mfma_f32_32x32x16_bf16(ab[0], bl[0], acc, 0, 0, 0);
            acc = __builtin_amdgcn_mfma_f32_32x32x16_bf16(ab[1], bl[1], acc, 0, 0, 0);
            acc = __builtin_amdgcn_mfma_f32_32x32x16_bf16(ab[2], bl[2], acc, 0, 0, 0);
            acc = __builtin_amdgcn_mfma_f32_32x32x16_bf16(ab[3], bl[3], acc, 0, 0, 0);

            // top-2, index packed into mantissa LSBs: 3 VALU/score
            unsigned enc = (unsigned)(2 * i + g2);   // 6-bit group id
#pragma unroll
            for (int r = 0; r < 16; ++r) {
                float sp = __uint_as_float(
                    (__float_as_uint(acc[r]) & 0xFFFFFFC0u) | enc);
                bv2[r] = __builtin_amdgcn_fmed3f(bv2[r], sp, bv[r]);
                bv[r]  = fmaxf(bv[r], sp);
            }
        }
        char* tsw = bA; bA = bB; bB = bC; bC = tsw;   // rotate ring
    }

    // ---- decode packed index, cross-col top-2 butterfly --------------------
    int bi[16];
#pragma unroll
    for (int r = 0; r < 16; ++r)
        bi[r] = (int)(__float_as_uint(bv[r]) & 63u) * 32 + col;  // within-half c
#pragma unroll
    for (int r = 0; r < 16; ++r) {
#pragma unroll
        for (int m = 1; m <= 16; m <<= 1) {
            float pv1 = __shfl_xor(bv[r],  m, 64);
            float pv2 = __shfl_xor(bv2[r], m, 64);
            int   pi  = __shfl_xor(bi[r],  m, 64);
            bool take = (pv1 > bv[r]) || (pv1 == bv[r] && pi < bi[r]);
            float lo1 = take ? bv[r] : pv1;
            bv2[r] = fmaxf(lo1, fmaxf(bv2[r], pv2));
            bv[r]  = take ? pv1 : bv[r];
            bi[r]  = take ? pi  : bi[r];
        }
    }
    if (col == 0) {                          // lanes 0 and 32
#pragma unroll
        for (int r = 0; r < 16; ++r) {
            int row = (r & 3) + 8 * (r >> 2) + 4 * kh;
            int q = q0 + w * 32 + row;
            size_t o = (size_t)pr * 4096 + q;
            wsv[o]  = bv[r];
            wsv2[o] = bv2[r];
            wsi[o]  = bi[r];
        }
    }
}

// ---- merge halves, margin flag, gather values -> out -----------------------
__global__ __launch_bounds__(256) void merge_out(const float* __restrict__ wsv,
                                                 const float* __restrict__ wsv2,
                                                 const int* __restrict__ wsi,
                                                 const float* __restrict__ values,
                                                 int* __restrict__ wl_count,
                                                 int* __restrict__ wl,
                                                 float* __restrict__ out) {
    __shared__ int fin[64];
    const int b = blockIdx.x;
    const int h = b >> 6;
    const int q0 = (b & 63) << 6;
    const int tid = threadIdx.x;
    if (tid < 64) {
        int q = q0 + tid;
        size_t p0 = (size_t)(h * 2) * 4096 + q, p1 = p0 + 4096;
        float a1 = wsv[p0], a2 = wsv2[p0];
        float b1 = wsv[p1], b2 = wsv2[p1];
        bool tb = b1 > a1;                   // tie -> half 0 (smaller c)
        float bvm = tb ? b1 : a1;
        int c = tb ? (2048 + wsi[p1]) : wsi[p0];
        float runner = fmaxf(fmaxf(a2, b2), fminf(a1, b1));
        fin[tid] = c;
        if (bvm - runner < TAUS) {
            int slot = atomicAdd(wl_count, 1);
            if (slot < WLCAP) wl[slot] = (h << 16) | q;
        }
    }
    __syncthreads();
#pragma unroll
    for (int k = 0; k < 4; ++k) {
        int f   = tid + k * 256;
        int row = f >> 4;
        int cl  = (f & 15) << 2;
        int idx = fin[row];
        float4 v = *reinterpret_cast<const float4*>(
            values + (size_t)h * CODES * DVI + (size_t)idx * DVI + cl);
        *reinterpret_cast<float4*>(
            out + (size_t)(q0 + row) * DIMX + h * DVI + cl) = v;
    }
}

// ---- pass 2: numpy-bit-exact re-argmin, 4 waves per flagged query ----------
__global__ __launch_bounds__(256) void np_recheck(const float* __restrict__ x,
                                                  const float* __restrict__ ke,
                                                  const float* __restrict__ values,
                                                  const float* __restrict__ e2np,
                                                  const int* __restrict__ wl_count,
                                                  const int* __restrict__ wl,
                                                  float* __restrict__ out) {
    __shared__ float xs[DKI];
    __shared__ float wv[4];
    __shared__ int   wi[4];
    __shared__ int   bcast;

    const int t = threadIdx.x, w = t >> 6, lane = t & 63;
    int cnt = *wl_count;
    if (cnt > WLCAP) cnt = WLCAP;

    for (int e = blockIdx.x; e < cnt; e += gridDim.x) {
        __syncthreads();
        int ent = wl[e];
        int h = ent >> 16, nq = ent & 0xffff;
        if (t < DKI) xs[t] = x[(size_t)nq * DIMX + h * DKI + t];
        __syncthreads();

        float x2 = np_sumsq64(xs);

        float best = 3.4e38f; int bestc = 0x7fffffff;
#pragma unroll 1
        for (int it = 0; it < 16; ++it) {
            int c = w * 1024 + it * 64 + lane;      // ascending per lane
            float er[DKI];
            const float4* p = reinterpret_cast<const float4*>(
                ke + ((size_t)h * CODES + c) * DKI);
#pragma unroll
            for (int i = 0; i < DKI / 4; ++i) {
                float4 v = p[i];
                er[i * 4 + 0] = v.x; er[i * 4 + 1] = v.y;
                er[i * 4 + 2] = v.z; er[i * 4 + 3] = v.w;
            }
            float dot = np_dot64(xs, er);
            float d2;
            {
#pragma clang fp contract(off)
                d2 = (x2 - 2.0f * dot) + e2np[h * CODES + c];
            }
            if (d2 < best) { best = d2; bestc = c; }
        }
        // 64-lane min butterfly with first-index tiebreak
#pragma unroll
        for (int m = 1; m <= 32; m <<= 1) {
            float pv = __shfl_xor(best, m, 64);
            int   pi = __shfl_xor(bestc, m, 64);
            if (pv < best || (pv == best && pi < bestc)) { best = pv; bestc = pi; }
        }
        if (lane == 0) { wv[w] = best; wi[w] = bestc; }
        __syncthreads();
        if (t == 0) {
            float bb = wv[0]; int bc = wi[0];
#pragma unroll
            for (int l = 1; l < 4; ++l)
                if (wv[l] < bb || (wv[l] == bb && wi[l] < bc)) { bb = wv[l]; bc = wi[l]; }
            bcast = bc;
        }
        __syncthreads();
        int c = bcast;
        if (t < DVI)
            out[(size_t)nq * DIMX + h * DVI + t] =
                values[((size_t)h * CODES + c) * DVI + t];
    }
}

extern "C" void kernel_launch(void* const* d_in, const int* in_sizes, int n_in,
                              void* d_out, int out_size, void* d_ws, size_t ws_size,
                              hipStream_t stream) {
    const float* x      = (const float*)d_in[0];
    // d_in[1] = mask (all ones; unused)
    const float* ke     = (const float*)d_in[2];
    const float* values = (const float*)d_in[3];
    // d_in[4] = key_optim (unused)
    float* out = (float*)d_out;

    char* ws = (char*)d_ws;
    float* e2np          = (float*)ws;          ws += (size_t)HEADS * CODES * 4;      // 196608
    unsigned short* m2bf = (unsigned short*)ws; ws += (size_t)HEADS * 2 * 2048 * 2;   // 98304
    float* wsv           = (float*)ws;          ws += (size_t)24 * 4096 * 4;          // 393216
    float* wsv2          = (float*)ws;          ws += (size_t)24 * 4096 * 4;
    int*   wsi           = (int*)ws;            ws += (size_t)24 * 4096 * 4;
    int*   wl_count      = (int*)ws;            ws += 64;
    int*   wl            = (int*)ws;            ws += (size_t)WLCAP * 4;              // 131072
    char*  EhT           = ws;                  ws += (size_t)HEADS * CODES * 128;    // 6291456
    char*  ElT           = ws;

    prep_ke<<<dim3((HEADS * CODES + 255) / 256), dim3(256), 0, stream>>>(
        ke, (uint4*)EhT, (uint4*)ElT, e2np, m2bf, wl_count);
    dkvb_pass1<<<dim3(768), dim3(256), 0, stream>>>(
        x, EhT, ElT, m2bf, wsv, wsv2, wsi);
    merge_out<<<dim3(768), dim3(256), 0, stream>>>(
        wsv, wsv2, wsi, values, wl_count, wl, out);
    np_recheck<<<dim3(1024), dim3(256), 0, stream>>>(
        x, ke, values, e2np, wl_count, wl, out);
}